// Round 1
// baseline (279.818 us; speedup 1.0000x reference)
//
#include <hip/hip_runtime.h>
#include <math.h>

#define B_    8
#define CIN   64
#define G_    4
#define CING  16
#define COUTG 32

// knots: t_i = -2.2 + 0.4*i, i=0..11  (GRID_LO - 3h .. GRID_HI + 3h, h=0.4)
__device__ __forceinline__ float knot(int i) { return -2.2f + 0.4f * (float)i; }

// ---------------------------------------------------------------------------
// Weight transpose: layer_weight (32, 144, 3, 3) ->
//   W2[icg][kh][kw][j][ocg], j in 0..8 (j<8: spline basis j, j==8: base/gelu)
// ---------------------------------------------------------------------------
__global__ void wtrans(const float* __restrict__ lw, float* __restrict__ w2) {
    int t = blockIdx.x * 256 + threadIdx.x;
    if (t >= 16 * 3 * 3 * 9 * 32) return;
    int ocg = t & 31;
    int j   = (t >> 5) % 9;
    int rem = t / 288;
    int kw  = rem % 3;
    int kh  = (rem / 3) % 3;
    int icg = rem / 9;
    int src;
    if (j < 8) src = ((ocg * 144 + icg * 8 + j) * 3 + kh) * 3 + kw;
    else       src = ((ocg * 144 + 128 + icg) * 3 + kh) * 3 + kw;
    w2[t] = lw[src];
}

// ---------------------------------------------------------------------------
// Fused feature + grouped conv. One block = one (b,g) pair, 16x16 spatial
// tile, all 32 output channels accumulated in registers.
// LDS: features F[y][x][12] (9 used), 48B element stride -> conflict-free.
// Weights read wave-uniform from W2 -> scalar loads (s_load), free operand.
// ---------------------------------------------------------------------------
__global__ __launch_bounds__(256) void kanconv(const float* __restrict__ x,
                                               const float* __restrict__ w2,
                                               float* __restrict__ y) {
    __shared__ __align__(16) float F[18 * 18 * 12];
    const int tid  = threadIdx.x;
    const int tile = blockIdx.x;     // 0..15 : 4x4 tiles of 16x16
    const int b    = blockIdx.y;     // 0..7
    const int g    = blockIdx.z;     // 0..3
    const int h0 = (tile >> 2) << 4;
    const int w0 = (tile & 3) << 4;
    const int ty = tid >> 4, tx = tid & 15;

    float acc[COUTG];
#pragma unroll
    for (int i = 0; i < COUTG; ++i) acc[i] = 0.f;

    const float* xg = x + ((size_t)(b * CIN + g * CING)) * 64 * 64;
    const int fbase = (ty * 18 + tx) * 12;

    for (int icg = 0; icg < CING; ++icg) {
        __syncthreads();  // protect F from readers of previous iteration
        // ---- stage features for this input channel (18x18 halo tile) ----
        for (int e = tid; e < 324; e += 256) {
            int yy = e / 18, xx = e - yy * 18;
            int hy = h0 - 1 + yy, wx = w0 - 1 + xx;
            float feat[12];
#pragma unroll
            for (int q = 0; q < 12; ++q) feat[q] = 0.f;
            if (((unsigned)hy < 64u) && ((unsigned)wx < 64u)) {
                float xv = xg[(icg * 64 + hy) * 64 + wx];
                // exact gelu
                feat[8] = 0.5f * xv * (1.0f + erff(xv * 0.70710678118654752f));
                // cubic B-spline bases (Cox-de Boor), 11 -> 10 -> 9 -> 8
                float bb[11];
#pragma unroll
                for (int i = 0; i < 11; ++i)
                    bb[i] = (xv >= knot(i) && xv < knot(i + 1)) ? 1.0f : 0.0f;
#pragma unroll
                for (int k = 1; k <= 3; ++k) {
#pragma unroll
                    for (int i = 0; i < 11; ++i) {
                        if (i < 11 - k) {
                            const float dl = 1.0f / (knot(i + k) - knot(i));
                            const float dr = 1.0f / (knot(i + k + 1) - knot(i + 1));
                            bb[i] = (xv - knot(i)) * dl * bb[i] +
                                    (knot(i + k + 1) - xv) * dr * bb[i + 1];
                        }
                    }
                }
#pragma unroll
                for (int j = 0; j < 8; ++j) feat[j] = bb[j];
            }
            float4* dst = (float4*)&F[e * 12];
            dst[0] = make_float4(feat[0], feat[1], feat[2],  feat[3]);
            dst[1] = make_float4(feat[4], feat[5], feat[6],  feat[7]);
            dst[2] = make_float4(feat[8], feat[9], feat[10], feat[11]);
        }
        __syncthreads();
        // ---- accumulate conv for this input channel ----
        const float* wp = w2 + icg * 2592;
        for (int t = 0; t < 9; ++t) {
            const int kh = t / 3, kw = t - kh * 3;
            const float4* fp = (const float4*)&F[fbase + (kh * 18 + kw) * 12];
            float4 fa = fp[0], fb = fp[1], fc = fp[2];
            float f[9] = {fa.x, fa.y, fa.z, fa.w, fb.x, fb.y, fb.z, fb.w, fc.x};
            const float* wq = wp + t * 288;   // wave-uniform -> s_load
#pragma unroll
            for (int j = 0; j < 9; ++j) {
#pragma unroll
                for (int oc = 0; oc < COUTG; ++oc)
                    acc[oc] = fmaf(wq[j * 32 + oc], f[j], acc[oc]);
            }
        }
    }

    const int h = h0 + ty, w = w0 + tx;
    float* yp = y + (((size_t)b * 128 + g * 32) * 64 + h) * 64 + w;
#pragma unroll
    for (int oc = 0; oc < COUTG; ++oc) yp[(size_t)oc * 4096] = acc[oc];
}

// ---------------------------------------------------------------------------
// Per-(b,c) mean / rstd over 64x64 spatial
// ---------------------------------------------------------------------------
__global__ __launch_bounds__(256) void stats(const float* __restrict__ y,
                                             float* __restrict__ st) {
    const int blk = blockIdx.x;  // b*128 + c
    const float4* yp = (const float4*)(y + (size_t)blk * 4096);
    float s = 0.f, s2 = 0.f;
    for (int i = threadIdx.x; i < 1024; i += 256) {
        float4 v = yp[i];
        s  += v.x + v.y + v.z + v.w;
        s2 += v.x * v.x + v.y * v.y + v.z * v.z + v.w * v.w;
    }
#pragma unroll
    for (int off = 32; off > 0; off >>= 1) {
        s  += __shfl_down(s, off);
        s2 += __shfl_down(s2, off);
    }
    __shared__ float red[8];
    int wave = threadIdx.x >> 6;
    if ((threadIdx.x & 63) == 0) { red[wave] = s; red[4 + wave] = s2; }
    __syncthreads();
    if (threadIdx.x == 0) {
        float S  = red[0] + red[1] + red[2] + red[3];
        float S2 = red[4] + red[5] + red[6] + red[7];
        float mean = S * (1.0f / 4096.0f);
        float var  = S2 * (1.0f / 4096.0f) - mean * mean;
        st[blk * 2]     = mean;
        st[blk * 2 + 1] = rsqrtf(var + 1e-5f);
    }
}

// ---------------------------------------------------------------------------
// In-place instance-norm + PReLU, float4 vectorized
// ---------------------------------------------------------------------------
__global__ __launch_bounds__(256) void normk(float* __restrict__ y,
                                             const float* __restrict__ st,
                                             const float* __restrict__ prelu) {
    int idx = blockIdx.x * 256 + threadIdx.x;   // float4 index, 0..1M-1
    int chanblk = idx >> 10;                    // b*128 + c  (1024 float4/chan)
    int gidx = (chanblk >> 5) & 3;
    float mean = st[chanblk * 2];
    float rstd = st[chanblk * 2 + 1];
    float slope = prelu[gidx];
    float4 v = ((const float4*)y)[idx];
    float4 o;
    float t;
    t = (v.x - mean) * rstd; o.x = t >= 0.f ? t : slope * t;
    t = (v.y - mean) * rstd; o.y = t >= 0.f ? t : slope * t;
    t = (v.z - mean) * rstd; o.z = t >= 0.f ? t : slope * t;
    t = (v.w - mean) * rstd; o.w = t >= 0.f ? t : slope * t;
    ((float4*)y)[idx] = o;
}

extern "C" void kernel_launch(void* const* d_in, const int* in_sizes, int n_in,
                              void* d_out, int out_size, void* d_ws, size_t ws_size,
                              hipStream_t stream) {
    const float* x     = (const float*)d_in[0];
    const float* lw    = (const float*)d_in[1];
    const float* prelu = (const float*)d_in[2];
    float* out = (float*)d_out;
    float* w2  = (float*)d_ws;                         // 41472 floats
    float* st  = (float*)((char*)d_ws + 41472 * 4);    // 1024*2 floats

    wtrans<<<162, 256, 0, stream>>>(lw, w2);
    dim3 grid(16, 8, 4);
    kanconv<<<grid, 256, 0, stream>>>(x, w2, out);
    stats<<<1024, 256, 0, stream>>>(out, st);
    normk<<<4096, 256, 0, stream>>>(out, st, prelu);
}

// Round 2
// 86.030 us; speedup vs baseline: 3.2526x; 3.2526x over previous
//
#include <hip/hip_runtime.h>
#include <hip/hip_bf16.h>
#include <math.h>

typedef __attribute__((ext_vector_type(8))) short short8;
typedef __attribute__((ext_vector_type(4))) float f32x4;

// ---------------------------------------------------------------------------
// Weight pack: layer_weight (32,144,3,3) f32 -> bf16 B-fragments, exact MFMA
// order. Page = (tap*5 + kstep)*2 + ntile (90 pages of 64 lanes x 8 bf16).
// k = jj*16 + icg, jj in 0..8 (8 = base/gelu), k in [144,160) zero pad.
// B-frag layout (16x16x32): col(oc) = lane&15, k = (lane>>4)*8 + e.
// ---------------------------------------------------------------------------
__global__ void wtrans(const float* __restrict__ lw, ushort* __restrict__ w2) {
    int t = blockIdx.x * 256 + threadIdx.x;
    if (t >= 46080) return;
    int e   = t & 7;
    int l   = (t >> 3) & 63;
    int nt  = (t >> 9) & 1;
    int ks  = (t >> 10) % 5;
    int tap = t / 5120;
    int oc  = nt * 16 + (l & 15);
    int k   = ks * 32 + (l >> 4) * 8 + e;
    int jj  = k >> 4, icg = k & 15;
    float val = 0.f;
    if (jj == 8)      val = lw[((oc * 144) + 128 + icg) * 9 + tap];
    else if (jj < 8)  val = lw[((oc * 144) + icg * 8 + jj) * 9 + tap];
    __hip_bfloat16 hb = __float2bfloat16(val);
    w2[t] = *(ushort*)&hb;
}

// ---------------------------------------------------------------------------
// MFMA implicit-GEMM KAN conv. Block = (b, g, 8x16 tile). Features for the
// 10x18 halo staged once in LDS as bf16, k-contiguous per pixel:
//   Fs[pixel*168 + jj*16 + icg], stride 336 B = 21 x 16B slots (2-way banks).
// 4 waves, each: 2 m-tiles (rows) x 2 n-tiles (oc) over 9 taps x 5 k-steps.
// ---------------------------------------------------------------------------
__global__ __launch_bounds__(256) void kanconv(const float* __restrict__ x,
                                               const ushort* __restrict__ w2,
                                               float* __restrict__ y) {
    __shared__ __align__(16) ushort Fs[180 * 168];
    const int tid  = threadIdx.x;
    const int tile = blockIdx.x;          // 0..31 : 8 row-tiles x 4 col-tiles
    const int b    = blockIdx.y;
    const int g    = blockIdx.z;
    const int h0 = (tile >> 2) * 8;
    const int w0 = (tile & 3) * 16;
    const float* xg = x + ((size_t)(b * 64 + g * 16)) * 4096;

    // ---- stage features (halo 10x18, 16 icg) ----
    for (int e = tid; e < 2880; e += 256) {
        int icg = e / 180;
        int p   = e - icg * 180;
        int py = p / 18, px = p - py * 18;
        int hy = h0 + py - 1, wx = w0 + px - 1;
        bool img = ((unsigned)hy < 64u) && ((unsigned)wx < 64u);
        float xv = img ? xg[icg * 4096 + hy * 64 + wx] : 0.f;
        // uniform cubic B-spline closed form; knots -2.2 + 0.4*i
        float tpos = (xv + 2.2f) * 2.5f;
        float cf = floorf(tpos);
        int ci = (int)cf;
        float u = tpos - cf;
        float u2 = u * u, u3 = u2 * u, om = 1.f - u;
        const float s6 = 1.f / 6.f;
        float q0 = om * om * om * s6;
        float q1 = (4.f - 6.f * u2 + 3.f * u3) * s6;
        float q2 = (1.f + 3.f * u + 3.f * u2 - 3.f * u3) * s6;
        float q3 = u3 * s6;
        bool inx = img && (ci >= 0) && (ci <= 10);
        ushort* row = &Fs[p * 168 + icg];
#pragma unroll
        for (int j = 0; j < 8; ++j) {
            int d = j - ci + 3;
            float v = inx ? ((d == 0) ? q0 : (d == 1) ? q1 : (d == 2) ? q2
                              : (d == 3) ? q3 : 0.f)
                          : 0.f;
            __hip_bfloat16 hb = __float2bfloat16(v);
            row[j * 16] = *(ushort*)&hb;
        }
        float ge = img ? 0.5f * xv * (1.f + erff(xv * 0.70710678118654752f)) : 0.f;
        __hip_bfloat16 hg = __float2bfloat16(ge);
        row[128] = *(ushort*)&hg;
    }
    // zero k in [144,160)
    {
        short8 z = {0, 0, 0, 0, 0, 0, 0, 0};
        for (int e = tid; e < 360; e += 256) {
            int p = e >> 1;
            *(short8*)&Fs[p * 168 + 144 + (e & 1) * 8] = z;
        }
    }
    __syncthreads();

    const int wv = tid >> 6;              // wave 0..3 -> rows 2w, 2w+1
    const int l  = tid & 63;
    const int lx = l & 15, q = l >> 4;
    const int lane_off = lx * 168 + q * 8;   // ushort units

    f32x4 acc00 = {0.f, 0.f, 0.f, 0.f};
    f32x4 acc01 = acc00, acc10 = acc00, acc11 = acc00;
    const short8* w8 = (const short8*)w2;

    for (int tap = 0; tap < 9; ++tap) {
        const int kh = tap / 3, kw = tap - kh * 3;
        const ushort* a0b = &Fs[((wv * 2 + kh) * 18 + kw) * 168 + lane_off];
        const ushort* a1b = a0b + 18 * 168;
#pragma unroll
        for (int ks = 0; ks < 5; ++ks) {
            short8 a0 = *(const short8*)(a0b + ks * 32);
            short8 a1 = *(const short8*)(a1b + ks * 32);
            short8 b0 = w8[((tap * 5 + ks) * 2 + 0) * 64 + l];
            short8 b1 = w8[((tap * 5 + ks) * 2 + 1) * 64 + l];
            acc00 = __builtin_amdgcn_mfma_f32_16x16x32_bf16(a0, b0, acc00, 0, 0, 0);
            acc01 = __builtin_amdgcn_mfma_f32_16x16x32_bf16(a0, b1, acc01, 0, 0, 0);
            acc10 = __builtin_amdgcn_mfma_f32_16x16x32_bf16(a1, b0, acc10, 0, 0, 0);
            acc11 = __builtin_amdgcn_mfma_f32_16x16x32_bf16(a1, b1, acc11, 0, 0, 0);
        }
    }

    // D layout: col(oc-in-tile) = lane&15, row(px) = (lane>>4)*4 + reg
    const int wcol = w0 + q * 4;
    float* yb = y + ((size_t)b * 128 + g * 32 + lx) * 4096;
    *(f32x4*)(yb + (h0 + wv * 2 + 0) * 64 + wcol)            = acc00;
    *(f32x4*)(yb + 16 * 4096 + (h0 + wv * 2 + 0) * 64 + wcol) = acc01;
    *(f32x4*)(yb + (h0 + wv * 2 + 1) * 64 + wcol)            = acc10;
    *(f32x4*)(yb + 16 * 4096 + (h0 + wv * 2 + 1) * 64 + wcol) = acc11;
}

// ---------------------------------------------------------------------------
// Per-(b,c) mean / rstd over 64x64 spatial
// ---------------------------------------------------------------------------
__global__ __launch_bounds__(256) void stats(const float* __restrict__ y,
                                             float* __restrict__ st) {
    const int blk = blockIdx.x;  // b*128 + c
    const float4* yp = (const float4*)(y + (size_t)blk * 4096);
    float s = 0.f, s2 = 0.f;
    for (int i = threadIdx.x; i < 1024; i += 256) {
        float4 v = yp[i];
        s  += v.x + v.y + v.z + v.w;
        s2 += v.x * v.x + v.y * v.y + v.z * v.z + v.w * v.w;
    }
#pragma unroll
    for (int off = 32; off > 0; off >>= 1) {
        s  += __shfl_down(s, off);
        s2 += __shfl_down(s2, off);
    }
    __shared__ float red[8];
    int wave = threadIdx.x >> 6;
    if ((threadIdx.x & 63) == 0) { red[wave] = s; red[4 + wave] = s2; }
    __syncthreads();
    if (threadIdx.x == 0) {
        float S  = red[0] + red[1] + red[2] + red[3];
        float S2 = red[4] + red[5] + red[6] + red[7];
        float mean = S * (1.0f / 4096.0f);
        float var  = S2 * (1.0f / 4096.0f) - mean * mean;
        st[blk * 2]     = mean;
        st[blk * 2 + 1] = rsqrtf(var + 1e-5f);
    }
}

// ---------------------------------------------------------------------------
// In-place instance-norm + PReLU, float4 vectorized
// ---------------------------------------------------------------------------
__global__ __launch_bounds__(256) void normk(float* __restrict__ y,
                                             const float* __restrict__ st,
                                             const float* __restrict__ prelu) {
    int idx = blockIdx.x * 256 + threadIdx.x;   // float4 index
    int chanblk = idx >> 10;                    // b*128 + c
    int gidx = (chanblk >> 5) & 3;
    float mean = st[chanblk * 2];
    float rstd = st[chanblk * 2 + 1];
    float slope = prelu[gidx];
    float4 v = ((const float4*)y)[idx];
    float4 o;
    float t;
    t = (v.x - mean) * rstd; o.x = t >= 0.f ? t : slope * t;
    t = (v.y - mean) * rstd; o.y = t >= 0.f ? t : slope * t;
    t = (v.z - mean) * rstd; o.z = t >= 0.f ? t : slope * t;
    t = (v.w - mean) * rstd; o.w = t >= 0.f ? t : slope * t;
    ((float4*)y)[idx] = o;
}

extern "C" void kernel_launch(void* const* d_in, const int* in_sizes, int n_in,
                              void* d_out, int out_size, void* d_ws, size_t ws_size,
                              hipStream_t stream) {
    const float* x     = (const float*)d_in[0];
    const float* lw    = (const float*)d_in[1];
    const float* prelu = (const float*)d_in[2];
    float*  out = (float*)d_out;
    ushort* w2  = (ushort*)d_ws;                        // 46080 bf16 = 92160 B
    float*  st  = (float*)((char*)d_ws + 92160);        // 1024*2 f32

    wtrans<<<180, 256, 0, stream>>>(lw, w2);
    dim3 grid(32, 8, 4);
    kanconv<<<grid, 256, 0, stream>>>(x, w2, out);
    stats<<<1024, 256, 0, stream>>>(out, st);
    normk<<<4096, 256, 0, stream>>>(out, st, prelu);
}

// Round 3
// 67.165 us; speedup vs baseline: 4.1661x; 1.2809x over previous
//
#include <hip/hip_runtime.h>
#include <hip/hip_bf16.h>
#include <math.h>

typedef __attribute__((ext_vector_type(8))) short short8;
typedef __attribute__((ext_vector_type(4))) float f32x4;

// ---------------------------------------------------------------------------
// Weight pack: layer_weight (32,144,3,3) f32 -> bf16 B-fragments, exact MFMA
// order. Page = (tap*5 + kstep)*2 + ntile (90 pages of 64 lanes x 8 bf16).
// k = jj*16 + icg, jj in 0..8 (8 = base/gelu), k in [144,160) zero pad.
// B-frag layout (16x16x32): col(oc) = lane&15, k = (lane>>4)*8 + e.
// ---------------------------------------------------------------------------
__global__ void wtrans(const float* __restrict__ lw, ushort* __restrict__ w2) {
    int t = blockIdx.x * 256 + threadIdx.x;
    if (t >= 46080) return;
    int e   = t & 7;
    int l   = (t >> 3) & 63;
    int nt  = (t >> 9) & 1;
    int ks  = (t >> 10) % 5;
    int tap = t / 5120;
    int oc  = nt * 16 + (l & 15);
    int k   = ks * 32 + (l >> 4) * 8 + e;
    int jj  = k >> 4, icg = k & 15;
    float val = 0.f;
    if (jj == 8)      val = lw[((oc * 144) + 128 + icg) * 9 + tap];
    else if (jj < 8)  val = lw[((oc * 144) + icg * 8 + jj) * 9 + tap];
    __hip_bfloat16 hb = __float2bfloat16(val);
    w2[t] = *(ushort*)&hb;
}

// ---------------------------------------------------------------------------
// MFMA implicit-GEMM KAN conv. Block = (b, g, 4x16 tile). Halo 6x18 = 108 px,
// 16 icg, features k-ordered jj*16+icg, row stride 168 ushort (336B).
// LDS 36.3KB -> 4 blocks/CU. 4 waves = {ntile} x {tap-half}; each wave does
// all 4 m-tiles (row 0..3) for its 20/25 k-steps; partials combined via LDS.
// ---------------------------------------------------------------------------
__global__ __launch_bounds__(256) void kanconv(const float* __restrict__ x,
                                               const ushort* __restrict__ w2,
                                               float* __restrict__ y) {
    __shared__ __align__(16) ushort Fs[108 * 168];
    const int tid  = threadIdx.x;
    const int tile = blockIdx.x;          // 0..63 : 16 row-tiles x 4 col-tiles
    const int b    = blockIdx.y;
    const int g    = blockIdx.z;
    const int h0 = (tile >> 2) * 4;
    const int w0 = (tile & 3) * 16;
    const float* xg = x + ((size_t)(b * 64 + g * 16)) * 4096;

    // ---- stage features (halo 6x18 = 108 px, 16 icg) ----
#pragma unroll 1
    for (int it = 0; it < 7; ++it) {
        int e = it * 256 + tid;
        if (e < 1728) {
            int icg = e / 108;
            int p   = e - icg * 108;
            int py = p / 18, px = p - py * 18;
            int hy = h0 + py - 1, wx = w0 + px - 1;
            bool img = ((unsigned)hy < 64u) && ((unsigned)wx < 64u);
            float xv = img ? xg[icg * 4096 + hy * 64 + wx] : 0.f;
            // uniform cubic B-spline closed form; knots -2.2 + 0.4*i
            float tpos = (xv + 2.2f) * 2.5f;
            float cf = floorf(tpos);
            int ci = (int)cf;
            float u = tpos - cf;
            float u2 = u * u, u3 = u2 * u, om = 1.f - u;
            const float s6 = 1.f / 6.f;
            float q0 = om * om * om * s6;
            float q1 = (4.f - 6.f * u2 + 3.f * u3) * s6;
            float q2 = (1.f + 3.f * u + 3.f * u2 - 3.f * u3) * s6;
            float q3 = u3 * s6;
            bool inx = img && (ci >= 0) && (ci <= 10);
            ushort* row = &Fs[p * 168 + icg];
#pragma unroll
            for (int j = 0; j < 8; ++j) {
                int d = j - ci + 3;
                float v = inx ? ((d == 0) ? q0 : (d == 1) ? q1 : (d == 2) ? q2
                                  : (d == 3) ? q3 : 0.f)
                              : 0.f;
                __hip_bfloat16 hb = __float2bfloat16(v);
                row[j * 16] = *(ushort*)&hb;
            }
            float ge = img ? 0.5f * xv * (1.f + erff(xv * 0.70710678118654752f)) : 0.f;
            __hip_bfloat16 hg = __float2bfloat16(ge);
            row[128] = *(ushort*)&hg;
        }
    }
    // zero pad k in [144,160)
    {
        short8 z = {0, 0, 0, 0, 0, 0, 0, 0};
        for (int e = tid; e < 216; e += 256) {
            int p = e >> 1;
            *(short8*)&Fs[p * 168 + 144 + (e & 1) * 8] = z;
        }
    }
    __syncthreads();

    const int wv = tid >> 6;
    const int l  = tid & 63;
    const int lx = l & 15, q = l >> 4;
    const int nt    = wv >> 1;            // 0,1 : oc tile
    const int khalf = wv & 1;             // 0: taps 0..4, 1: taps 5..8
    const int tap_lo = khalf ? 5 : 0;
    const int tap_hi = khalf ? 9 : 5;

    f32x4 acc0 = {0.f, 0.f, 0.f, 0.f};
    f32x4 acc1 = acc0, acc2 = acc0, acc3 = acc0;
    const short8* w8 = (const short8*)w2;
    const int lane_off = (lx)*168 + q * 8;   // col part (add row*18*168)

#pragma unroll 1
    for (int tap = tap_lo; tap < tap_hi; ++tap) {
        const int kh = tap / 3, kw = tap - kh * 3;
        const ushort* arow = &Fs[(kh * 18 + kw) * 168 + lane_off];
        const short8* bp = w8 + (tap * 10 + nt) * 64 + l;
#pragma unroll
        for (int ks = 0; ks < 5; ++ks) {
            short8 bf = bp[ks * 128];
            short8 a0 = *(const short8*)(arow + 0 * 3024 + ks * 32);
            short8 a1 = *(const short8*)(arow + 1 * 3024 + ks * 32);
            short8 a2 = *(const short8*)(arow + 2 * 3024 + ks * 32);
            short8 a3 = *(const short8*)(arow + 3 * 3024 + ks * 32);
            acc0 = __builtin_amdgcn_mfma_f32_16x16x32_bf16(a0, bf, acc0, 0, 0, 0);
            acc1 = __builtin_amdgcn_mfma_f32_16x16x32_bf16(a1, bf, acc1, 0, 0, 0);
            acc2 = __builtin_amdgcn_mfma_f32_16x16x32_bf16(a2, bf, acc2, 0, 0, 0);
            acc3 = __builtin_amdgcn_mfma_f32_16x16x32_bf16(a3, bf, acc3, 0, 0, 0);
        }
    }

    // ---- combine tap-halves through LDS (reuse Fs) ----
    __syncthreads();                      // everyone done reading Fs
    float* comb = (float*)Fs;             // [nt][lane][16]
    if (khalf == 1) {
        float* cp = comb + (nt * 64 + l) * 16;
        *(f32x4*)(cp + 0)  = acc0;
        *(f32x4*)(cp + 4)  = acc1;
        *(f32x4*)(cp + 8)  = acc2;
        *(f32x4*)(cp + 12) = acc3;
    }
    __syncthreads();
    if (khalf == 0) {
        const float* cp = comb + (nt * 64 + l) * 16;
        f32x4 o0 = acc0 + *(const f32x4*)(cp + 0);
        f32x4 o1 = acc1 + *(const f32x4*)(cp + 4);
        f32x4 o2 = acc2 + *(const f32x4*)(cp + 8);
        f32x4 o3 = acc3 + *(const f32x4*)(cp + 12);
        // D layout: col(oc-in-tile) = lx, px = q*4 + reg; rows = m-tile 0..3
        float* yb = y + ((size_t)b * 128 + g * 32 + nt * 16 + lx) * 4096
                      + h0 * 64 + w0 + q * 4;
        *(f32x4*)(yb + 0 * 64) = o0;
        *(f32x4*)(yb + 1 * 64) = o1;
        *(f32x4*)(yb + 2 * 64) = o2;
        *(f32x4*)(yb + 3 * 64) = o3;
    }
}

// ---------------------------------------------------------------------------
// Per-(b,c) mean / rstd over 64x64 spatial
// ---------------------------------------------------------------------------
__global__ __launch_bounds__(256) void stats(const float* __restrict__ y,
                                             float* __restrict__ st) {
    const int blk = blockIdx.x;  // b*128 + c
    const float4* yp = (const float4*)(y + (size_t)blk * 4096);
    float s = 0.f, s2 = 0.f;
    for (int i = threadIdx.x; i < 1024; i += 256) {
        float4 v = yp[i];
        s  += v.x + v.y + v.z + v.w;
        s2 += v.x * v.x + v.y * v.y + v.z * v.z + v.w * v.w;
    }
#pragma unroll
    for (int off = 32; off > 0; off >>= 1) {
        s  += __shfl_down(s, off);
        s2 += __shfl_down(s2, off);
    }
    __shared__ float red[8];
    int wave = threadIdx.x >> 6;
    if ((threadIdx.x & 63) == 0) { red[wave] = s; red[4 + wave] = s2; }
    __syncthreads();
    if (threadIdx.x == 0) {
        float S  = red[0] + red[1] + red[2] + red[3];
        float S2 = red[4] + red[5] + red[6] + red[7];
        float mean = S * (1.0f / 4096.0f);
        float var  = S2 * (1.0f / 4096.0f) - mean * mean;
        st[blk * 2]     = mean;
        st[blk * 2 + 1] = rsqrtf(var + 1e-5f);
    }
}

// ---------------------------------------------------------------------------
// In-place instance-norm + PReLU, float4 vectorized
// ---------------------------------------------------------------------------
__global__ __launch_bounds__(256) void normk(float* __restrict__ y,
                                             const float* __restrict__ st,
                                             const float* __restrict__ prelu) {
    int idx = blockIdx.x * 256 + threadIdx.x;   // float4 index
    int chanblk = idx >> 10;                    // b*128 + c
    int gidx = (chanblk >> 5) & 3;
    float mean = st[chanblk * 2];
    float rstd = st[chanblk * 2 + 1];
    float slope = prelu[gidx];
    float4 v = ((const float4*)y)[idx];
    float4 o;
    float t;
    t = (v.x - mean) * rstd; o.x = t >= 0.f ? t : slope * t;
    t = (v.y - mean) * rstd; o.y = t >= 0.f ? t : slope * t;
    t = (v.z - mean) * rstd; o.z = t >= 0.f ? t : slope * t;
    t = (v.w - mean) * rstd; o.w = t >= 0.f ? t : slope * t;
    ((float4*)y)[idx] = o;
}

extern "C" void kernel_launch(void* const* d_in, const int* in_sizes, int n_in,
                              void* d_out, int out_size, void* d_ws, size_t ws_size,
                              hipStream_t stream) {
    const float* x     = (const float*)d_in[0];
    const float* lw    = (const float*)d_in[1];
    const float* prelu = (const float*)d_in[2];
    float*  out = (float*)d_out;
    ushort* w2  = (ushort*)d_ws;                        // 46080 bf16 = 92160 B
    float*  st  = (float*)((char*)d_ws + 92160);        // 1024*2 f32

    wtrans<<<180, 256, 0, stream>>>(lw, w2);
    dim3 grid(64, 8, 4);
    kanconv<<<grid, 256, 0, stream>>>(x, w2, out);
    stats<<<1024, 256, 0, stream>>>(out, st);
    normk<<<4096, 256, 0, stream>>>(out, st, prelu);
}

// Round 4
// 42.797 us; speedup vs baseline: 6.5382x; 1.5694x over previous
//
#include <hip/hip_runtime.h>
#include <hip/hip_bf16.h>
#include <math.h>

typedef __attribute__((ext_vector_type(8))) short short8;
typedef __attribute__((ext_vector_type(4))) float f32x4;

// ---------------------------------------------------------------------------
// Weight pack: layer_weight (32,144,3,3) f32 -> bf16 B-fragments.
// K-order: k<128 -> spline (icg*8+jj)  [= lw's own channel order!],
//          128<=k<144 -> base/gelu (icg), k in [144,160) zero pad.
// Page = (tap*5 + ks)*2 + nt, 64 lanes x 8 bf16 per page.
// B-frag (16x16x32): col(oc) = lane&15, k = ks*32 + (lane>>4)*8 + e.
// ---------------------------------------------------------------------------
__global__ void wtrans(const float* __restrict__ lw, ushort* __restrict__ w2) {
    int t = blockIdx.x * 256 + threadIdx.x;
    if (t >= 5760) return;
    int l    = t & 63;
    int page = t >> 6;
    int nt  = page & 1;
    int ks  = (page >> 1) % 5;
    int tap = page / 10;
    int oc = nt * 16 + (l & 15);
    int kbase = ks * 32 + (l >> 4) * 8;
    short8 v;
#pragma unroll
    for (int e = 0; e < 8; ++e) {
        int k = kbase + e;
        float val = (k < 144) ? lw[(oc * 144 + k) * 9 + tap] : 0.f;
        __hip_bfloat16 hb = __float2bfloat16(val);
        v[e] = *(short*)&hb;
    }
    ((short8*)w2)[t] = v;
}

// ---------------------------------------------------------------------------
// MFMA implicit-GEMM KAN conv. Block = (b, g, 4x16 tile). Halo 6x18 = 108 px,
// row stride 168 ushort (336B = 84 dw = 20 mod 32 -> conflict-free b128).
// Staging: per (p,icg) ONE aligned b128 (8 spline bf16) + 1 ushort (gelu).
// 4 waves = {ntile} x {tap-half}; 4 m-tiles each; partials combined via LDS.
// ---------------------------------------------------------------------------
__global__ __launch_bounds__(256) void kanconv(const float* __restrict__ x,
                                               const ushort* __restrict__ w2,
                                               float* __restrict__ y) {
    __shared__ __align__(16) ushort Fs[108 * 168];
    const int tid  = threadIdx.x;
    const int tile = blockIdx.x;          // 0..63 : 16 row-tiles x 4 col-tiles
    const int b    = blockIdx.y;
    const int g    = blockIdx.z;
    const int h0 = (tile >> 2) * 4;
    const int w0 = (tile & 3) * 16;
    const float* xg = x + ((size_t)(b * 64 + g * 16)) * 4096;

    // ---- stage features (halo 6x18 = 108 px, 16 icg) ----
#pragma unroll 1
    for (int it = 0; it < 7; ++it) {
        int e = it * 256 + tid;
        if (e < 1728) {
            int icg = e / 108;
            int p   = e - icg * 108;
            int py = p / 18, px = p - py * 18;
            int hy = h0 + py - 1, wx = w0 + px - 1;
            bool img = ((unsigned)hy < 64u) && ((unsigned)wx < 64u);
            float xv = img ? xg[icg * 4096 + hy * 64 + wx] : 0.f;
            // uniform cubic B-spline closed form; knots -2.2 + 0.4*i
            float tpos = (xv + 2.2f) * 2.5f;
            float cf = floorf(tpos);
            int ci = (int)cf;
            float u = tpos - cf;
            float u2 = u * u, u3 = u2 * u, om = 1.f - u;
            const float s6 = 1.f / 6.f;
            float q0 = om * om * om * s6;
            float q1 = (4.f - 6.f * u2 + 3.f * u3) * s6;
            float q2 = (1.f + 3.f * u + 3.f * u2 - 3.f * u3) * s6;
            float q3 = u3 * s6;
            // pack q0..q3 (bf16) into uint64, funnel-shift into 8-slot row:
            // slot j gets q_{j-ci+3}  <=>  Q << 16*(ci-3)
            __hip_bfloat16 hq0 = __float2bfloat16(q0);
            __hip_bfloat16 hq1 = __float2bfloat16(q1);
            __hip_bfloat16 hq2 = __float2bfloat16(q2);
            __hip_bfloat16 hq3 = __float2bfloat16(q3);
            unsigned long long Q =
                  (unsigned long long)*(ushort*)&hq0
                | ((unsigned long long)*(ushort*)&hq1 << 16)
                | ((unsigned long long)*(ushort*)&hq2 << 32)
                | ((unsigned long long)*(ushort*)&hq3 << 48);
            unsigned long long lo = 0, hi = 0;
            if (img && ci >= 0 && ci <= 10) {
                int s = ci * 16 - 48;
                if (s < 0)        { lo = Q >> (-s); }
                else if (s < 64)  { lo = Q << s; hi = s ? (Q >> (64 - s)) : 0ull; }
                else              { hi = Q << (s - 64); }
            }
            union { unsigned long long u64[2]; short8 s8; } un;
            un.u64[0] = lo; un.u64[1] = hi;
            ushort* row = &Fs[p * 168];
            *(short8*)(row + icg * 8) = un.s8;
            // gelu via branch-free poly erf (A&S 7.1.26)
            float z  = xv * 0.70710678118654752f;
            float az = fabsf(z);
            float tt = 1.f / fmaf(0.3275911f, az, 1.f);
            float poly = tt * fmaf(tt, fmaf(tt, fmaf(tt, fmaf(tt, 1.061405429f,
                          -1.453152027f), 1.421413741f), -0.284496736f),
                          0.254829592f);
            float er = 1.f - poly * __expf(-z * z);
            er = (z < 0.f) ? -er : er;
            float ge = 0.5f * xv * (1.f + er);
            __hip_bfloat16 hg = __float2bfloat16(ge);
            row[128 + icg] = *(ushort*)&hg;
        }
    }
    // zero pad k in [144,160)
    {
        short8 z8 = {0, 0, 0, 0, 0, 0, 0, 0};
        for (int e = tid; e < 216; e += 256) {
            int p = e >> 1;
            *(short8*)&Fs[p * 168 + 144 + (e & 1) * 8] = z8;
        }
    }
    __syncthreads();

    const int wv = tid >> 6;
    const int l  = tid & 63;
    const int lx = l & 15, q = l >> 4;
    const int nt    = wv >> 1;            // 0,1 : oc tile
    const int khalf = wv & 1;             // 0: taps 0..4, 1: taps 5..8
    const int tap_lo = khalf ? 5 : 0;
    const int tap_hi = khalf ? 9 : 5;

    f32x4 acc0 = {0.f, 0.f, 0.f, 0.f};
    f32x4 acc1 = acc0, acc2 = acc0, acc3 = acc0;
    const short8* w8 = (const short8*)w2;
    const int lane_off = lx * 168 + q * 8;

#pragma unroll 1
    for (int tap = tap_lo; tap < tap_hi; ++tap) {
        const int kh = tap / 3, kw = tap - kh * 3;
        const ushort* arow = &Fs[(kh * 18 + kw) * 168 + lane_off];
        const short8* bp = w8 + (tap * 10 + nt) * 64 + l;
#pragma unroll
        for (int ks = 0; ks < 5; ++ks) {
            short8 bf = bp[ks * 128];
            short8 a0 = *(const short8*)(arow + 0 * 3024 + ks * 32);
            short8 a1 = *(const short8*)(arow + 1 * 3024 + ks * 32);
            short8 a2 = *(const short8*)(arow + 2 * 3024 + ks * 32);
            short8 a3 = *(const short8*)(arow + 3 * 3024 + ks * 32);
            acc0 = __builtin_amdgcn_mfma_f32_16x16x32_bf16(a0, bf, acc0, 0, 0, 0);
            acc1 = __builtin_amdgcn_mfma_f32_16x16x32_bf16(a1, bf, acc1, 0, 0, 0);
            acc2 = __builtin_amdgcn_mfma_f32_16x16x32_bf16(a2, bf, acc2, 0, 0, 0);
            acc3 = __builtin_amdgcn_mfma_f32_16x16x32_bf16(a3, bf, acc3, 0, 0, 0);
        }
    }

    // ---- combine tap-halves through LDS (reuse Fs; stride 20 dw = no bank dup)
    __syncthreads();
    float* comb = (float*)Fs;             // [nt][lane] stride 20 floats
    if (khalf == 1) {
        float* cp = comb + (nt * 64 + l) * 20;
        *(f32x4*)(cp + 0)  = acc0;
        *(f32x4*)(cp + 4)  = acc1;
        *(f32x4*)(cp + 8)  = acc2;
        *(f32x4*)(cp + 12) = acc3;
    }
    __syncthreads();
    if (khalf == 0) {
        const float* cp = comb + (nt * 64 + l) * 20;
        f32x4 o0 = acc0 + *(const f32x4*)(cp + 0);
        f32x4 o1 = acc1 + *(const f32x4*)(cp + 4);
        f32x4 o2 = acc2 + *(const f32x4*)(cp + 8);
        f32x4 o3 = acc3 + *(const f32x4*)(cp + 12);
        // D layout: col(oc-in-tile) = lx, px = q*4 + reg; rows = m-tile 0..3
        float* yb = y + ((size_t)b * 128 + g * 32 + nt * 16 + lx) * 4096
                      + h0 * 64 + w0 + q * 4;
        *(f32x4*)(yb + 0 * 64) = o0;
        *(f32x4*)(yb + 1 * 64) = o1;
        *(f32x4*)(yb + 2 * 64) = o2;
        *(f32x4*)(yb + 3 * 64) = o3;
    }
}

// ---------------------------------------------------------------------------
// Fused instance-norm + PReLU: one block per (b,c); 16 floats/thread held in
// registers across the reduction -> single read + single write of y.
// ---------------------------------------------------------------------------
__global__ __launch_bounds__(256) void instnorm(float* __restrict__ y,
                                                const float* __restrict__ prelu) {
    const int blk = blockIdx.x;  // b*128 + c
    const int tid = threadIdx.x;
    float4* yp = (float4*)(y + (size_t)blk * 4096);
    float4 v0 = yp[tid], v1 = yp[tid + 256], v2 = yp[tid + 512], v3 = yp[tid + 768];
    float s  = v0.x + v0.y + v0.z + v0.w + v1.x + v1.y + v1.z + v1.w
             + v2.x + v2.y + v2.z + v2.w + v3.x + v3.y + v3.z + v3.w;
    float s2 = v0.x*v0.x + v0.y*v0.y + v0.z*v0.z + v0.w*v0.w
             + v1.x*v1.x + v1.y*v1.y + v1.z*v1.z + v1.w*v1.w
             + v2.x*v2.x + v2.y*v2.y + v2.z*v2.z + v2.w*v2.w
             + v3.x*v3.x + v3.y*v3.y + v3.z*v3.z + v3.w*v3.w;
#pragma unroll
    for (int off = 32; off > 0; off >>= 1) {
        s  += __shfl_down(s, off);
        s2 += __shfl_down(s2, off);
    }
    __shared__ float red[8];
    int wave = tid >> 6;
    if ((tid & 63) == 0) { red[wave] = s; red[4 + wave] = s2; }
    __syncthreads();
    float S  = red[0] + red[1] + red[2] + red[3];
    float S2 = red[4] + red[5] + red[6] + red[7];
    float mean = S * (1.0f / 4096.0f);
    float var  = S2 * (1.0f / 4096.0f) - mean * mean;
    float rstd = rsqrtf(var + 1e-5f);
    float slope = prelu[(blk >> 5) & 3];
    float t;
    float4 o;
#define NRM(vv)                                                               \
    t = (vv.x - mean) * rstd; o.x = t >= 0.f ? t : slope * t;                 \
    t = (vv.y - mean) * rstd; o.y = t >= 0.f ? t : slope * t;                 \
    t = (vv.z - mean) * rstd; o.z = t >= 0.f ? t : slope * t;                 \
    t = (vv.w - mean) * rstd; o.w = t >= 0.f ? t : slope * t;
    NRM(v0); yp[tid]       = o;
    NRM(v1); yp[tid + 256] = o;
    NRM(v2); yp[tid + 512] = o;
    NRM(v3); yp[tid + 768] = o;
#undef NRM
}

extern "C" void kernel_launch(void* const* d_in, const int* in_sizes, int n_in,
                              void* d_out, int out_size, void* d_ws, size_t ws_size,
                              hipStream_t stream) {
    const float* x     = (const float*)d_in[0];
    const float* lw    = (const float*)d_in[1];
    const float* prelu = (const float*)d_in[2];
    float*  out = (float*)d_out;
    ushort* w2  = (ushort*)d_ws;                        // 46080 bf16 = 92160 B

    wtrans<<<23, 256, 0, stream>>>(lw, w2);
    dim3 grid(64, 8, 4);
    kanconv<<<grid, 256, 0, stream>>>(x, w2, out);
    instnorm<<<1024, 256, 0, stream>>>(out, prelu);
}